// Round 10
// baseline (3299.879 us; speedup 1.0000x reference)
//
#include <hip/hip_runtime.h>

#define TST   1024
#define OWN   16           // own tile: 16x16
#define HALO  8            // 8 rings -> 8 stages -> 2 RK4 steps per exchange
#define TDIM  32           // 32x32 tile = own 16x16 + 8-halo
#define NT    512          // 8 waves; thread t owns cells (tr,c) and (tr+16,c)
#define NW    8
#define NB    256          // 16x16 blocks, one per CU

typedef float v4f __attribute__((ext_vector_type(4)));

#define AG __HIP_MEMORY_SCOPE_AGENT
__device__ __forceinline__ float agload (const float* p){ return __hip_atomic_load (p, __ATOMIC_RELAXED, AG); }
__device__ __forceinline__ int   agloadi(const int* p)  { return __hip_atomic_load (p, __ATOMIC_RELAXED, AG); }
__device__ __forceinline__ void  agstoref(float* p,float v){      __hip_atomic_store(p, v, __ATOMIC_RELAXED, AG); }
__device__ __forceinline__ void  agstorei(int* p,int v) {         __hip_atomic_store(p, v, __ATOMIC_RELAXED, AG); }

// Device-scope (sc1) 16B accesses, coherent at Infinity Cache. Stamp rides in
// .w -> each halo cell self-validates. Load+waitcnt in ONE asm block.
__device__ __forceinline__ v4f ld16_dev(const v4f* p) {
    v4f r;
    asm volatile("global_load_dwordx4 %0, %1, off sc1\n\ts_waitcnt vmcnt(0)"
                 : "=v"(r) : "v"(p) : "memory");
    return r;
}
__device__ __forceinline__ void st16_dev(v4f* p, v4f v) {
    asm volatile("global_store_dwordx4 %0, %1, off sc1" :: "v"(p), "v"(v) : "memory");
}

__global__ void __launch_bounds__(NT)
mm_solver(const float* __restrict__ signal,
          const float* __restrict__ B_ext,
          const float* __restrict__ Msat,
          const float* __restrict__ src_mask,
          const float* __restrict__ probe_mask,
          float* __restrict__ out,
          float* __restrict__ ws)
{
    const int b  = (int)blockIdx.x;
    const int bx = b & 15, by = b >> 4;
    const int t  = (int)threadIdx.x;
    const int tr = t >> 5;                   // 0..15 (cell0 row; cell1 = tr+16)
    const int c  = t & 31;                   // tile column 0..31
    const int wv = t >> 6;                   // wave id 0..7

    // DIAGNOSTIC COARSENING (R8/R9 failed; R6/R7 passed): 2 cells/thread at
    // rows (tr) and (tr+16) -- 16 rows apart, so NO register neighbors, NO
    // strip logic. Every cell runs R7's verified per-cell code verbatim
    // (duplicated with suffix 0/1). Isolates {multi-cell mechanics} from
    // {adjacent-strip register-neighbor logic}. Upside: 8-wave barriers,
    // 2 independent chains/thread overlap LDS read latency with math.

    const int gcol  = bx * OWN - HALO + c;
    const int grow0 = by * OWN - HALO + tr;        // cell0: tile row tr
    const int grow1 = grow0 + 16;                  // cell1: tile row tr+16
    const bool colIn = (gcol >= 0 && gcol < 256);
    const bool inG0 = colIn && (grow0 >= 0 && grow0 < 256);
    const bool inG1 = colIn && (grow1 >= 0 && grow1 < 256);
    const bool ownC = (c >= HALO && c < HALO + OWN);
    const bool own0 = ownC && (tr >= HALO);                 // tile row in [8,16)
    const bool own1 = ownC && (tr + 16 < HALO + OWN);       // tile row in [16,24)

    // ws: pub v4f[2][65536] (2MB) | priv float[NB][TST] (1MB) | doneA int[NB]
    v4f*   pub   = (v4f*)ws;
    float* priv  = ws + 2 * 65536 * 4;
    int*   doneA = (int*)(priv + NB * TST);
    const int pubStride = 65536;

    __shared__ v4f  EB[2][TDIM * TDIM];      // 32 KB exposure buffers
    __shared__ float sigS[TST];
    __shared__ int   hasP;
    __shared__ int   pfl[NB];
    __shared__ float redS[NW];
    __shared__ float pmsS;

    // Phase sync = ONE hardware s_barrier per stage (8/group), 8 waves.
    // Double-buffer hazard proof unchanged from R7 (verified): phase p writes
    // EB[p&1] -> lgkmcnt(0)+barrier -> reads EB[p&1]; the overwrite of
    // EB[(p+1)&1] (read at phase p-1) is separated from those reads by the
    // phase-p barrier (reads drained by the waitcnt preceding it).
#define PSYNC() do { \
    asm volatile("s_waitcnt lgkmcnt(0)" ::: "memory"); \
    __builtin_amdgcn_s_barrier(); \
    asm volatile("" ::: "memory"); \
} while (0)

    const bool lane0 = ((t & 63) == 0);

    // constants (identical fp expressions to the bitwise-validated kernels)
    const float invd   = (float)(1.0 / (double)((float)(50e-9 * 50e-9)));
    const float h      = (float)(1.7595e11 * 5e-12);
    const float hh     = (float)(0.5 * (1.7595e11 * 5e-12));
    const float h6     = (float)((1.7595e11 * 5e-12) / 6.0);
    const float alpha  = 0.01f;
    const float inv1a2 = (float)(1.0 / (1.0 + 0.01 * 0.01));

    const int gcolc = gcol < 0 ? 0 : (gcol > 255 ? 255 : gcol);

    // Per-cell field constants + per-cell clamp offsets -- VERBATIM R7 logic,
    // instantiated twice (suffix 0: row tr; suffix 1: row tr+16).
#define LOADC(J, GROW, TROW) \
    const int grc##J  = (GROW) < 0 ? 0 : ((GROW) > 255 ? 255 : (GROW)); \
    const int idxg##J = grc##J * 256 + gcolc; \
    const float bxv##J = B_ext[idxg##J], byv##J = B_ext[65536 + idxg##J], bzv##J = B_ext[131072 + idxg##J]; \
    const float ms##J  = Msat[idxg##J]; \
    const float sxv##J = src_mask[idxg##J], syv##J = src_mask[65536 + idxg##J], szv##J = src_mask[131072 + idxg##J]; \
    const float pm##J  = probe_mask[idxg##J]; \
    const float ce##J  = 7.3e-12f / ms##J; \
    const float cd##J  = -(float)(4.0e-7 * 3.14159265358979323846) * ms##J; \
    const int idx##J  = (TROW) * TDIM + c; \
    const int offU##J = (((TROW) < TDIM - 1) && ((GROW) < 255)) ?  TDIM : 0; \
    const int offD##J = (((TROW) > 0)        && ((GROW) > 0))   ? -TDIM : 0;
    LOADC(0, grow0, tr)
    LOADC(1, grow1, tr + 16)
    const int offR = ((c < TDIM - 1) && (gcol < 255)) ?  1 : 0;
    const int offL = ((c > 0)        && (gcol > 0))   ? -1 : 0;

    // relax() is bitwise identity; m0 = z-hat exactly. Group 0 needs no halo
    // poll; owners pre-stamp parity-1 with -1 so no garbage stamp validates.
    float m0x = 0.0f, m0y = 0.0f, m0z = 1.0f;
    float m1x = 0.0f, m1y = 0.0f, m1z = 1.0f;

    if (own0) {
        st16_dev(pub + idxg0,             (v4f){0.0f, 0.0f, 1.0f, __int_as_float(0)});
        st16_dev(pub + pubStride + idxg0, (v4f){0.0f, 0.0f, 1.0f, __int_as_float(-1)});
    }
    if (own1) {
        st16_dev(pub + idxg1,             (v4f){0.0f, 0.0f, 1.0f, __int_as_float(0)});
        st16_dev(pub + pubStride + idxg1, (v4f){0.0f, 0.0f, 1.0f, __int_as_float(-1)});
    }
    for (int k = t; k < TST; k += NT) sigS[k] = signal[k];
    if (t == 40) hasP = 0;
    __syncthreads();
    const bool pc0 = own0 && (pm0 != 0.0f);
    const bool pc1 = own1 && (pm1 != 0.0f);
    const bool pAny = pc0 || pc1;
    if (pAny) atomicOr(&hasP, 1);
    const bool waveP = (__ballot(pAny) != 0ull);   // wave-uniform
    __syncthreads();
    const int hasPr = hasP;
    if (hasPr) for (int k = t; k < TST; k += NT) agstoref(&priv[b * TST + k], 0.0f);
    __syncthreads();   // drain zero-stores before step-0 probe atomics

    const bool halo0 = inG0 && !own0;
    const bool halo1 = inG1 && !own1;

    float e0x, e0y, e0z, e1x, e1y, e1z;
    float a0x, a0y, a0z, a1x, a1y, a1z;
    float k0x, k0y, k0z, k1x, k1y, k1z;
    float bt0x, bt0y, bt0z, bt1x, bt1y, bt1z;

    // R7's STAGE, parameterized by cell suffix. All 4 neighbors from LDS,
    // same clamp-to-self offsets, identical fp expression order.
#define STAGEX(J, SB) do { \
    const v4f u = EB[SB][idx##J + offU##J]; \
    const v4f d = EB[SB][idx##J + offD##J]; \
    const v4f r = EB[SB][idx##J + offR]; \
    const v4f l = EB[SB][idx##J + offL]; \
    float lpx = ((u.x + d.x - 2.0f * e##J##x) + (r.x + l.x - 2.0f * e##J##x)) * invd; \
    float lpy = ((u.y + d.y - 2.0f * e##J##y) + (r.y + l.y - 2.0f * e##J##y)) * invd; \
    float lpz = ((u.z + d.z - 2.0f * e##J##z) + (r.z + l.z - 2.0f * e##J##z)) * invd; \
    float Bx = bt##J##x + ce##J * lpx; \
    float By = bt##J##y + ce##J * lpy; \
    float Bz = bt##J##z + ce##J * lpz + cd##J * e##J##z; \
    float cx = e##J##y * Bz - e##J##z * By; \
    float cy = e##J##z * Bx - e##J##x * Bz; \
    float cz = e##J##x * By - e##J##y * Bx; \
    float dx_ = e##J##y * cz - e##J##z * cy; \
    float dy_ = e##J##z * cx - e##J##x * cz; \
    float dz_ = e##J##x * cy - e##J##y * cx; \
    k##J##x = -(cx + alpha * dx_) * inv1a2; \
    k##J##y = -(cy + alpha * dy_) * inv1a2; \
    k##J##z = -(cz + alpha * dz_) * inv1a2; \
} while (0)

#define STAGE(SB) do { STAGEX(0, SB); STAGEX(1, SB); } while (0)

#define WRE(DB) do { \
    EB[DB][idx0] = (v4f){e0x, e0y, e0z, 0.0f}; \
    EB[DB][idx1] = (v4f){e1x, e1y, e1z, 0.0f}; \
} while (0)

#define FOR2(M)    M(0) M(1)
#define EASSIGN(J) e##J##x = m##J##x; e##J##y = m##J##y; e##J##z = m##J##z;
#define AINIT(J)   a##J##x = k##J##x; a##J##y = k##J##y; a##J##z = k##J##z;
#define AACC2(J)   a##J##x += 2.0f*k##J##x; a##J##y += 2.0f*k##J##y; a##J##z += 2.0f*k##J##z;
#define AACC1(J)   a##J##x += k##J##x; a##J##y += k##J##y; a##J##z += k##J##z;
#define EHH(J)     e##J##x = m##J##x + hh*k##J##x; e##J##y = m##J##y + hh*k##J##y; e##J##z = m##J##z + hh*k##J##z;
#define EH(J)      e##J##x = m##J##x + h*k##J##x;  e##J##y = m##J##y + h*k##J##y;  e##J##z = m##J##z + h*k##J##z;
#define MUPD(J)    m##J##x += h6*a##J##x; m##J##y += h6*a##J##y; m##J##z += h6*a##J##z;
#define BTSET(J,S) bt##J##x = bxv##J + (S)*sxv##J; bt##J##y = byv##J + (S)*syv##J; bt##J##z = bzv##J + (S)*szv##J;

// One full RK4 step: 4 phases (write -> barrier -> stencil), signal S.
// Structure verbatim R7, each op done for both cells.
#define RK4_STEP(S) do { \
    BTSET(0,S) BTSET(1,S) \
    FOR2(EASSIGN) \
    WRE(0);  PSYNC();  STAGE(0);       /* k1 */ \
    FOR2(AINIT) \
    FOR2(EHH) \
    WRE(1);  PSYNC();  STAGE(1);       /* k2 */ \
    FOR2(AACC2) \
    FOR2(EHH) \
    WRE(0);  PSYNC();  STAGE(0);       /* k3 */ \
    FOR2(AACC2) \
    FOR2(EH) \
    WRE(1);  PSYNC();  STAGE(1);       /* k4 */ \
    FOR2(AACC1) \
    FOR2(MUPD) \
} while (0)

#define PROBE(I_) do { \
    if (waveP) { \
        float cc = (pc0 ? m0x * ms0 * pm0 : 0.0f) + (pc1 ? m1x * ms1 * pm1 : 0.0f); \
        _Pragma("unroll") \
        for (int off = 32; off > 0; off >>= 1) cc += __shfl_down(cc, off, 64); \
        if (lane0) atomicAdd(&priv[b * TST + (I_)], cc); \
    } \
} while (0)

    for (int i = 0; i < TST; i += 2) {
        const int I = i >> 1;                 // 2-step group index

        // Halo refresh ONCE per group: R7's exact per-cell poll loop, run
        // independently for each of the thread's two cells. Skipped at I==0
        // (m_0 analytic). Miss -> s_sleep(1) backoff. Cross-block chain
        // strictly decreases group index -> no premature overwrite/deadlock.
        if (halo0 && I) {
            const v4f* p = pub + (I & 1) * pubStride + idxg0;
            for (;;) {
                v4f hv = ld16_dev(p);
                if (__float_as_int(hv.w) >= I) { m0x = hv.x; m0y = hv.y; m0z = hv.z; break; }
                __builtin_amdgcn_s_sleep(1);
            }
        }
        if (halo1 && I) {
            const v4f* p = pub + (I & 1) * pubStride + idxg1;
            for (;;) {
                v4f hv = ld16_dev(p);
                if (__float_as_int(hv.w) >= I) { m1x = hv.x; m1y = hv.y; m1z = hv.z; break; }
                __builtin_amdgcn_s_sleep(1);
            }
        }

        RK4_STEP(sigS[i]);                    // step A -> m_{i+1}
        PROBE(i);
        RK4_STEP(sigS[i + 1]);                // step B -> m_{i+2}
        PROBE(i + 1);

        // publish m_{i+2}, stamp I+1, parity (I+1)&1 (fire-and-forget, global)
        {
            v4f* pp = pub + ((I + 1) & 1) * pubStride;
            const float st = __int_as_float(I + 1);
            if (own0) st16_dev(pp + idxg0, (v4f){m0x, m0y, m0z, st});
            if (own1) st16_dev(pp + idxg1, (v4f){m1x, m1y, m1z, st});
        }
    }

    // ---- finalize ----
    __syncthreads();   // TRUE barrier: drains vmcnt -> publishes/atomics done
    if (t == 0) agstorei(&doneA[b], 0x5D0000 | hasPr);

    if (b == 0) {
        if (t < NB) {
            int v;
            for (;;) { v = agloadi(&doneA[t]); if ((v & ~1) == 0x5D0000) break;
                       __builtin_amdgcn_s_sleep(8); }
            pfl[t] = v & 1;
        }
        __syncthreads();
        float ps = 0.0f;
        for (int k = t; k < 65536; k += NT) ps += probe_mask[k];
        #pragma unroll
        for (int off = 32; off > 0; off >>= 1) ps += __shfl_down(ps, off, 64);
        if (lane0) redS[wv] = ps;
        __syncthreads();
        if (t == 0) { float q = 0.0f; for (int w = 0; w < NW; ++w) q += redS[w]; pmsS = q; }
        __syncthreads();
        const float pms = pmsS;
        for (int o = t; o < TST; o += NT) {
            float sm = 0.0f;
            for (int j = 0; j < NB; ++j) if (pfl[j]) sm += agload(&priv[j * TST + o]);
            out[o] = sm / pms;
        }
    }
}

extern "C" void kernel_launch(void* const* d_in, const int* in_sizes, int n_in,
                              void* d_out, int out_size, void* d_ws, size_t ws_size,
                              hipStream_t stream)
{
    const float* signal = (const float*)d_in[0];
    const float* B_ext  = (const float*)d_in[1];
    const float* Msat   = (const float*)d_in[2];
    const float* src    = (const float*)d_in[3];
    const float* probe  = (const float*)d_in[4];
    float* out = (float*)d_out;
    float* ws  = (float*)d_ws;

    void* args[] = { &signal, &B_ext, &Msat, &src, &probe, &out, &ws };
    (void)in_sizes; (void)n_in; (void)out_size; (void)ws_size;

    // 256 blocks (16x16 own tiles, 8-deep halo) x 512 threads: thread t owns
    // the two cells (tr,c) and (tr+16,c) -- R7's verified per-cell code run
    // twice per thread (all-LDS stencil, per-cell polls/publishes/clamps).
    // 8-wave barriers + 2 independent chains/thread for latency overlap.
    // Phase sync = one hw s_barrier per stage; cross-block exchange every
    // 2 RK4 steps via stamped IF$ slots.
    hipLaunchCooperativeKernel(reinterpret_cast<void*>(mm_solver),
                               dim3(NB), dim3(NT), args, 0, stream);
}

// Round 11
// 2641.523 us; speedup vs baseline: 1.2492x; 1.2492x over previous
//
#include <hip/hip_runtime.h>

#define TST   1024
#define OWN   16           // own tile: 16x16
#define HALO  8            // 8 rings -> 8 stages -> 2 RK4 steps per exchange
#define TDIM  32           // 32x32 tile = own 16x16 + 8-halo
#define NT    1024         // 16 waves; wave w owns tile rows {2w, 2w+1}
#define NW    16
#define NB    256          // 16x16 blocks, one per CU

typedef float v4f __attribute__((ext_vector_type(4)));

#define AG __HIP_MEMORY_SCOPE_AGENT
__device__ __forceinline__ float agload (const float* p){ return __hip_atomic_load (p, __ATOMIC_RELAXED, AG); }
__device__ __forceinline__ int   agloadi(const int* p)  { return __hip_atomic_load (p, __ATOMIC_RELAXED, AG); }
__device__ __forceinline__ void  agstoref(float* p,float v){      __hip_atomic_store(p, v, __ATOMIC_RELAXED, AG); }
__device__ __forceinline__ void  agstorei(int* p,int v) {         __hip_atomic_store(p, v, __ATOMIC_RELAXED, AG); }

// Device-scope (sc1) 16B accesses, coherent at Infinity Cache. Stamp rides in
// .w -> each halo cell self-validates. Load+waitcnt in ONE asm block.
__device__ __forceinline__ v4f ld16_dev(const v4f* p) {
    v4f r;
    asm volatile("global_load_dwordx4 %0, %1, off sc1\n\ts_waitcnt vmcnt(0)"
                 : "=v"(r) : "v"(p) : "memory");
    return r;
}
__device__ __forceinline__ void st16_dev(v4f* p, v4f v) {
    asm volatile("global_store_dwordx4 %0, %1, off sc1" :: "v"(p), "v"(v) : "memory");
}

__global__ void __launch_bounds__(NT)
mm_solver(const float* __restrict__ signal,
          const float* __restrict__ B_ext,
          const float* __restrict__ Msat,
          const float* __restrict__ src_mask,
          const float* __restrict__ probe_mask,
          float* __restrict__ out,
          float* __restrict__ ws)
{
    const int b  = (int)blockIdx.x;
    const int bx = b & 15, by = b >> 4;
    const int t  = (int)threadIdx.x;
    const int tr = t >> 5, tc = t & 31;      // 32-wide rows, rank == t
    const int wv = t >> 6;                   // wave id 0..15

    const int grow = by * OWN - HALO + tr;
    const int gcol = bx * OWN - HALO + tc;
    const bool inG = (grow >= 0 && grow < 256 && gcol >= 0 && gcol < 256);
    const bool own = (tr >= HALO && tr < HALO + OWN && tc >= HALO && tc < HALO + OWN);

    // CONE PREDICATION (R11): dOwn = L1 distance from this cell to the own
    // 16x16 region in tile coords. A cell's stage-s value influences own cells
    // (by stage 8) iff dOwn <= 8-s. So: write exposure phase p iff dOwn <= 8-p;
    // compute stage s iff dOwn <= 8-s. Cell-phase work 8192 -> ~4200 per
    // group; row-halo waves go FULLY idle progressively (wave-level DS/VALU
    // issue -25%). Correctness is STRONGER than R7: tile-edge cells never
    // compute a stencil, so tile-edge garbage is never generated; every
    // consumed value is exact (consumer at stage s has d<=8-s; its neighbors
    // have d<=9-s and wrote phase s-1 under the d<=8-(s-1) rule). Cells with
    // d>8 do nothing at all (not even the phase-0 m-write; nothing reads them).
    const int dyO = (tr < HALO) ? (HALO - tr) : ((tr > 23) ? (tr - 23) : 0);
    const int dxO = (tc < HALO) ? (HALO - tc) : ((tc > 23) ? (tc - 23) : 0);
    const int dOwn = dxO + dyO;

    // ws: pub v4f[2][65536] (2MB) | priv float[NB][TST] (1MB) | doneA int[NB]
    v4f*   pub   = (v4f*)ws;
    float* priv  = ws + 2 * 65536 * 4;
    int*   doneA = (int*)(priv + NB * TST);
    const int pubStride = 65536;

    __shared__ v4f  EB[2][TDIM * TDIM];      // 32 KB exposure buffers
    __shared__ float sigS[TST];
    __shared__ int   hasP;
    __shared__ int   pfl[NB];
    __shared__ float redS[NW];
    __shared__ float pmsS;

    // Phase sync = ONE hardware s_barrier per stage (8/group), 16 waves.
    // Double-buffer hazard proof unchanged from R7 (verified): phase p writes
    // EB[p&1] -> lgkmcnt(0)+barrier -> reads EB[p&1]; the overwrite of
    // EB[(p+1)&1] (read at phase p-1) is separated from those reads by the
    // phase-p barrier (reads drained by the waitcnt preceding it). PSYNC is
    // OUTSIDE all predicates -> every wave executes all 8 barriers/group.
#define PSYNC() do { \
    asm volatile("s_waitcnt lgkmcnt(0)" ::: "memory"); \
    __builtin_amdgcn_s_barrier(); \
    asm volatile("" ::: "memory"); \
} while (0)

    const bool lane0 = ((t & 63) == 0);

    // constants (identical fp expressions to the bitwise-validated kernels)
    const float invd   = (float)(1.0 / (double)((float)(50e-9 * 50e-9)));
    const float h      = (float)(1.7595e11 * 5e-12);
    const float hh     = (float)(0.5 * (1.7595e11 * 5e-12));
    const float h6     = (float)((1.7595e11 * 5e-12) / 6.0);
    const float alpha  = 0.01f;
    const float inv1a2 = (float)(1.0 / (1.0 + 0.01 * 0.01));

    const int growc = grow < 0 ? 0 : (grow > 255 ? 255 : grow);
    const int gcolc = gcol < 0 ? 0 : (gcol > 255 ? 255 : gcol);
    const int idxg  = growc * 256 + gcolc;
    const float bxv = B_ext[idxg], byv = B_ext[65536 + idxg], bzv = B_ext[131072 + idxg];
    const float ms  = Msat[idxg];
    const float sxv = src_mask[idxg], syv = src_mask[65536 + idxg], szv = src_mask[131072 + idxg];
    const float pm  = probe_mask[idxg];
    const float ce   = 7.3e-12f / ms;
    const float cdem = -(float)(4.0e-7 * 3.14159265358979323846) * ms;

    // Neighbor offsets: physical Neumann clamp (exact) + tile-edge clamp.
    // With predication the tile-edge clamp is never exercised by an active
    // stencil at a stage where it could matter (active cells have all true
    // neighbors written); kept verbatim for bitwise identity. Row-uniform.
    const int idx  = t;
    const int offU = ((tr < TDIM - 1) && (grow < 255)) ?  TDIM : 0;
    const int offD = ((tr > 0)        && (grow > 0))   ? -TDIM : 0;
    const int offR = ((tc < TDIM - 1) && (gcol < 255)) ?  1 : 0;
    const int offL = ((tc > 0)        && (gcol > 0))   ? -1 : 0;

    const int slotOff = idxg;                 // poll slot (own: == publish slot)

    // relax() is bitwise identity; m0 = z-hat exactly. Group 0 needs no halo
    // poll; owners pre-stamp parity-1 with -1 so no garbage stamp validates.
    float mx = 0.0f, my = 0.0f, mz = 1.0f;

    if (own) {
        st16_dev(pub + slotOff,             (v4f){0.0f, 0.0f, 1.0f, __int_as_float(0)});
        st16_dev(pub + pubStride + slotOff, (v4f){0.0f, 0.0f, 1.0f, __int_as_float(-1)});
    }
    for (int k = t; k < TST; k += NT) sigS[k] = signal[k];
    if (t == 40) hasP = 0;
    __syncthreads();
    const bool pcell = own && (pm != 0.0f);
    if (pcell) atomicOr(&hasP, 1);
    const bool waveP = (__ballot(pcell) != 0ull);   // wave-uniform
    __syncthreads();
    const int hasPr = hasP;
    if (hasPr) for (int k = t; k < TST; k += NT) agstoref(&priv[b * TST + k], 0.0f);
    __syncthreads();   // drain zero-stores before step-0 probe atomics

    // Poll only cells that participate (dOwn <= 8); d>8 corners never write.
    const bool haloT = inG && !own && (dOwn <= HALO);
    float ex, ey, ez, ax, ay, az, kx, ky, kz, btx, bty, btz;

#define STAGE(SB) do { \
    const v4f u = EB[SB][idx + offU]; \
    const v4f d = EB[SB][idx + offD]; \
    const v4f r = EB[SB][idx + offR]; \
    const v4f l = EB[SB][idx + offL]; \
    float lx = ((u.x + d.x - 2.0f * ex) + (r.x + l.x - 2.0f * ex)) * invd; \
    float ly = ((u.y + d.y - 2.0f * ey) + (r.y + l.y - 2.0f * ey)) * invd; \
    float lz = ((u.z + d.z - 2.0f * ez) + (r.z + l.z - 2.0f * ez)) * invd; \
    float Bx = btx + ce * lx; \
    float By = bty + ce * ly; \
    float Bz = btz + ce * lz + cdem * ez; \
    float cx = ey * Bz - ez * By; \
    float cy = ez * Bx - ex * Bz; \
    float cz = ex * By - ey * Bx; \
    float dx = ey * cz - ez * cy; \
    float dy = ez * cx - ex * cz; \
    float dz = ex * cy - ey * cx; \
    kx = -(cx + alpha * dx) * inv1a2; \
    ky = -(cy + alpha * dy) * inv1a2; \
    kz = -(cz + alpha * dz) * inv1a2; \
} while (0)

#define WRE(DB) do { EB[DB][idx] = (v4f){ex, ey, ez, 0.0f}; } while (0)

// One full RK4 step with cone predication. A = phase budget at step entry
// (8 for step A of a group, 4 for step B). Op order between barriers is
// EXACTLY R7's: [WRE] B [STAGE..WRE] B [STAGE..WRE] B [STAGE..WRE] B [STAGE..]
#define RK4_STEP(S, A) do { \
    if (dOwn <= (A)) { \
        btx = bxv + (S) * sxv;  bty = byv + (S) * syv;  btz = bzv + (S) * szv; \
        ex = mx; ey = my; ez = mz; \
        WRE(0); \
    } \
    PSYNC(); \
    if (dOwn <= (A) - 1) { \
        STAGE(0);                          /* k1 */ \
        ax = kx; ay = ky; az = kz; \
        ex = mx + hh * kx; ey = my + hh * ky; ez = mz + hh * kz; \
        WRE(1); \
    } \
    PSYNC(); \
    if (dOwn <= (A) - 2) { \
        STAGE(1);                          /* k2 */ \
        ax += 2.0f * kx; ay += 2.0f * ky; az += 2.0f * kz; \
        ex = mx + hh * kx; ey = my + hh * ky; ez = mz + hh * kz; \
        WRE(0); \
    } \
    PSYNC(); \
    if (dOwn <= (A) - 3) { \
        STAGE(0);                          /* k3 */ \
        ax += 2.0f * kx; ay += 2.0f * ky; az += 2.0f * kz; \
        ex = mx + h * kx; ey = my + h * ky; ez = mz + h * kz; \
        WRE(1); \
    } \
    PSYNC(); \
    if (dOwn <= (A) - 4) { \
        STAGE(1);                          /* k4 */ \
        ax += kx; ay += ky; az += kz; \
        mx += h6 * ax; my += h6 * ay; mz += h6 * az; \
    } \
} while (0)

#define PROBE(I_) do { \
    if (waveP) { \
        float c = pcell ? mx * ms * pm : 0.0f; \
        _Pragma("unroll") \
        for (int off = 32; off > 0; off >>= 1) c += __shfl_down(c, off, 64); \
        if (lane0) atomicAdd(&priv[b * TST + (I_)], c); \
    } \
} while (0)

    for (int i = 0; i < TST; i += 2) {
        const int I = i >> 1;                 // 2-step group index

        // Halo refresh ONCE per group: poll my cell's stamped slot (parity
        // I&1) until stamp>=I. Skipped at I==0 (m_0 analytic) and for cells
        // with dOwn>8 (never participate). Miss -> s_sleep(1) backoff.
        // Cross-block chain strictly decreases group index -> no premature
        // overwrite, no deadlock (proof as R5-R7).
        if (haloT && I) {
            const v4f* p = pub + (I & 1) * pubStride + slotOff;
            for (;;) {
                v4f hv = ld16_dev(p);
                if (__float_as_int(hv.w) >= I) { mx = hv.x; my = hv.y; mz = hv.z; break; }
                __builtin_amdgcn_s_sleep(1);
            }
        }

        RK4_STEP(sigS[i],     8);             // step A -> m_{i+1} (d<=4 cells)
        PROBE(i);
        RK4_STEP(sigS[i + 1], 4);             // step B -> m_{i+2} (own cells)
        PROBE(i + 1);

        // publish m_{i+2}, stamp I+1, parity (I+1)&1 (fire-and-forget, global)
        if (own) st16_dev(pub + ((I + 1) & 1) * pubStride + slotOff,
                          (v4f){mx, my, mz, __int_as_float(I + 1)});
    }

    // ---- finalize ----
    __syncthreads();   // TRUE barrier: drains vmcnt -> publishes/atomics done
    if (t == 0) agstorei(&doneA[b], 0x5D0000 | hasPr);

    if (b == 0) {
        if (t < NB) {
            int v;
            for (;;) { v = agloadi(&doneA[t]); if ((v & ~1) == 0x5D0000) break;
                       __builtin_amdgcn_s_sleep(8); }
            pfl[t] = v & 1;
        }
        __syncthreads();
        float ps = 0.0f;
        for (int k = t; k < 65536; k += NT) ps += probe_mask[k];
        #pragma unroll
        for (int off = 32; off > 0; off >>= 1) ps += __shfl_down(ps, off, 64);
        if (lane0) redS[wv] = ps;
        __syncthreads();
        if (t == 0) { float q = 0.0f; for (int w = 0; w < NW; ++w) q += redS[w]; pmsS = q; }
        __syncthreads();
        const float pms = pmsS;
        for (int o = t; o < TST; o += NT) {
            float sm = 0.0f;
            for (int j = 0; j < NB; ++j) if (pfl[j]) sm += agload(&priv[j * TST + o]);
            out[o] = sm / pms;
        }
    }
}

extern "C" void kernel_launch(void* const* d_in, const int* in_sizes, int n_in,
                              void* d_out, int out_size, void* d_ws, size_t ws_size,
                              hipStream_t stream)
{
    const float* signal = (const float*)d_in[0];
    const float* B_ext  = (const float*)d_in[1];
    const float* Msat   = (const float*)d_in[2];
    const float* src    = (const float*)d_in[3];
    const float* probe  = (const float*)d_in[4];
    float* out = (float*)d_out;
    float* ws  = (float*)d_ws;

    void* args[] = { &signal, &B_ext, &Msat, &src, &probe, &out, &ws };
    (void)in_sizes; (void)n_in; (void)out_size; (void)ws_size;

    // 256 blocks (16x16 own tiles, 8-deep halo) x 1024 threads, 1 cell/thread
    // (R7 verified structure) + CONE PREDICATION: cell participates in phase p
    // iff its L1 distance to the own region satisfies d <= 8-p. Row-halo waves
    // go fully idle progressively (DS/VALU wave-issue -25%); tile-edge garbage
    // is never generated. Phase sync = one hw s_barrier per stage; cross-block
    // exchange every 2 RK4 steps via stamped IF$ slots.
    hipLaunchCooperativeKernel(reinterpret_cast<void*>(mm_solver),
                               dim3(NB), dim3(NT), args, 0, stream);
}